// Round 12
// baseline (77.659 us; speedup 1.0000x reference)
//
#include <hip/hip_runtime.h>
#include <hip/hip_fp16.h>

#define D       128
#define NROWS   100000
#define NBN     (NROWS / 16)     // 6250 N-convert blocks
#define GRID_G  1024             // gather blocks: 1024*4 waves * 4 groups = 16384 = 262144/16

typedef __attribute__((ext_vector_type(8))) _Float16 f16x8;
typedef __attribute__((ext_vector_type(4))) float    f32x4;

union F16x8U { _Float16 h[8]; f16x8 v; };
union F32x4U { float f[4]; f32x4 v; };

typedef __attribute__((address_space(1))) const void gvoid;
typedef __attribute__((address_space(3))) void       lvoid;

// ---------------------------------------------------------------------------
// Kernel 0: metric -> fragment-ordered fp16 B-fragments (hi only, 32 KB).
// Slot q = (kk*8+cf)*64+lane holds M[k0+j][col], col = cf*16+(lane&15),
// k0 = kk*32+(lane>>4)*8 — the verified 16x16x32 MFMA B-operand layout.
// ---------------------------------------------------------------------------
__global__ __launch_bounds__(256) void convert_M16(
    const float* __restrict__ M, _Float16* __restrict__ mh)
{
    const int q    = blockIdx.x * 256 + threadIdx.x;  // [0, 2048)
    const int kk   = q >> 9;
    const int cf   = (q >> 6) & 7;
    const int lane = q & 63;
    const int col  = cf * 16 + (lane & 15);
    const int k0   = kk * 32 + (lane >> 4) * 8;

    F16x8U h;
    #pragma unroll
    for (int j = 0; j < 8; ++j) h.h[j] = (_Float16)M[(k0 + j) * D + col];
    *(f16x8*)(mh + q * 8) = h.v;
}

// ---------------------------------------------------------------------------
// Kernel 1: N -> fp16 in pi order, pi(c) = (c&15)*8 + (c>>4)  (proven R6).
// 16 rows/block; thread (row, l16) reads 8 dwords at stride 64B (coalesced
// per 16-lane group) -> one 16B store.
// ---------------------------------------------------------------------------
__global__ __launch_bounds__(256) void conv_N(
    const float* __restrict__ N, _Float16* __restrict__ Np)
{
    const int l16 = threadIdx.x & 15;
    const int row = blockIdx.x * 16 + (threadIdx.x >> 4);   // exact: NBN*16 = NROWS
    const float* src = N + (size_t)row * D + l16;
    F16x8U o;
    #pragma unroll
    for (int k = 0; k < 8; ++k) o.h[k] = (_Float16)src[16 * k];
    *(f16x8*)(Np + (size_t)row * D + l16 * 8) = o.v;
}

// ---------------------------------------------------------------------------
// Kernel 2: fused gather + on-the-fly bilinear form via MFMA.
// Per 16-output group (one wave):
//   T = X @ M   where X = 16 gathered E rows (A-frag: row = lane&15 -> random
//               row xs[o0+lrow]; k = kk*32 + (lane>>4)*8; fp32 load + cvt),
//               M from 32KB LDS B-fragments (staged once/block, R10 pattern).
//   T's C/D layout (m89-verified): lane holds T[lk*4+i][cf*16+lrow].
//   out[r] = sigmoid(2*dot(T[r], N[y_r]) - 1): lane multiplies its 8 T-cols
//   by Np16[y_r][lrow*8+cf] (pi order == exactly those cols), sums in-lane
//   over cf, reduces over the 16-lane lrow group (shfl_xor 1,2,4,8).
// No barriers after the one-time M stage; free-running gather waves.
// ---------------------------------------------------------------------------
__global__ __launch_bounds__(256, 3) void gather_mfma(
    const int* __restrict__ xs, const int* __restrict__ ys,
    const float* __restrict__ E, const _Float16* __restrict__ Np,
    const _Float16* __restrict__ mh, float* __restrict__ out)
{
    __shared__ _Float16 sm[2048 * 8];   // 32 KB, B-fragment slots

    const int tid  = threadIdx.x;
    const int lane = tid & 63;
    const int w    = tid >> 6;
    const int lrow = lane & 15;
    const int lk   = lane >> 4;

    // One-time stage of M fragments (linear copy; wave-uniform LDS base).
    #pragma unroll
    for (int it = 0; it < 8; ++it) {
        const int slot = it * 256 + w * 64 + lane;
        __builtin_amdgcn_global_load_lds(
            (gvoid*)(mh + slot * 8), (lvoid*)(sm + (it * 256 + w * 64) * 8),
            16, 0, 0);
    }
    asm volatile("s_waitcnt vmcnt(0)" ::: "memory");
    __syncthreads();

    const f16x8* Bh = (const f16x8*)sm;   // [(kk*8+cf)*64 + lane]

    const int wgid = (int)blockIdx.x * 4 + w;   // 0..4095

    #pragma unroll 1
    for (int t = 0; t < 4; ++t) {
        const int o0 = (wgid * 4 + t) * 16;

        // Indices: A-row for this lane; 4 y-rows for this lk-group.
        const int xi = xs[o0 + lrow];
        const int4 y4 = *(const int4*)(ys + o0 + lk * 4);

        // E loads (fp32, 2 x 16B per kk; 128B granules per gathered row).
        f32x4 ex0, ex1, ex2, ex3, ey0, ey1, ey2, ey3;
        {
            const float* p = E + (size_t)xi * D + lk * 8;
            ex0 = *(const f32x4*)(p);        ey0 = *(const f32x4*)(p + 4);
            ex1 = *(const f32x4*)(p + 32);   ey1 = *(const f32x4*)(p + 36);
            ex2 = *(const f32x4*)(p + 64);   ey2 = *(const f32x4*)(p + 68);
            ex3 = *(const f32x4*)(p + 96);   ey3 = *(const f32x4*)(p + 100);
        }

        // N loads (fp16 pi-order, one 16B per row).
        const f16x8 nf0 = *(const f16x8*)(Np + (size_t)y4.x * D + lrow * 8);
        const f16x8 nf1 = *(const f16x8*)(Np + (size_t)y4.y * D + lrow * 8);
        const f16x8 nf2 = *(const f16x8*)(Np + (size_t)y4.z * D + lrow * 8);
        const f16x8 nf3 = *(const f16x8*)(Np + (size_t)y4.w * D + lrow * 8);

        f32x4 acc[8];
        #pragma unroll
        for (int cf = 0; cf < 8; ++cf) acc[cf] = (f32x4){0.f, 0.f, 0.f, 0.f};

        #pragma unroll
        for (int kk = 0; kk < 4; ++kk) {
            F32x4U x, y;
            if (kk == 0) { x.v = ex0; y.v = ey0; }
            else if (kk == 1) { x.v = ex1; y.v = ey1; }
            else if (kk == 2) { x.v = ex2; y.v = ey2; }
            else { x.v = ex3; y.v = ey3; }
            F16x8U a16;
            #pragma unroll
            for (int j = 0; j < 4; ++j) {
                a16.h[j]     = (_Float16)x.f[j];
                a16.h[j + 4] = (_Float16)y.f[j];
            }
            #pragma unroll
            for (int cf = 0; cf < 8; ++cf)
                acc[cf] = __builtin_amdgcn_mfma_f32_16x16x32_f16(
                    a16.v, Bh[(kk * 8 + cf) * 64 + lane], acc[cf], 0, 0, 0);
        }

        // Elementwise with N + in-lane cf-sum: p_i = sum_cf T[r_i][cf*16+lrow]
        // * N[y_{r_i}][cf*16+lrow], r_i = lk*4+i.
        float p0 = 0.f, p1 = 0.f, p2 = 0.f, p3 = 0.f;
        #pragma unroll
        for (int cf = 0; cf < 8; ++cf) {
            p0 += acc[cf][0] * (float)nf0[cf];
            p1 += acc[cf][1] * (float)nf1[cf];
            p2 += acc[cf][2] * (float)nf2[cf];
            p3 += acc[cf][3] * (float)nf3[cf];
        }

        // Reduce across the 16-lane lrow group.
        #pragma unroll
        for (int m = 1; m < 16; m <<= 1) {
            p0 += __shfl_xor(p0, m);
            p1 += __shfl_xor(p1, m);
            p2 += __shfl_xor(p2, m);
            p3 += __shfl_xor(p3, m);
        }

        if (lrow < 4) {
            const float dsel = lrow == 0 ? p0 : lrow == 1 ? p1 : lrow == 2 ? p2 : p3;
            out[o0 + lk * 4 + lrow] = 1.0f / (1.0f + __expf(1.0f - 2.0f * dsel));
        }
    }
}

extern "C" void kernel_launch(void* const* d_in, const int* in_sizes, int n_in,
                              void* d_out, int out_size, void* d_ws, size_t ws_size,
                              hipStream_t stream) {
    const int*   xs     = (const int*)d_in[0];
    const int*   ys     = (const int*)d_in[1];
    const float* metric = (const float*)d_in[2];
    const float* EMBEDM = (const float*)d_in[3];
    const float* NEGEM  = (const float*)d_in[4];
    float*       out    = (float*)d_out;

    // d_ws layout: Np16 25.6MB @0, M-fragments (hi, 32KB) @32MB.
    char* ws = (char*)d_ws;
    _Float16* Np = (_Float16*)ws;
    _Float16* mh = (_Float16*)(ws + (32u << 20));

    convert_M16<<<8, 256, 0, stream>>>(metric, mh);

    conv_N<<<NBN, 256, 0, stream>>>(NEGEM, Np);

    gather_mfma<<<GRID_G, 256, 0, stream>>>(xs, ys, EMBEDM, Np, mh, out);
}

// Round 13
// 56.320 us; speedup vs baseline: 1.3789x; 1.3789x over previous
//
#include <hip/hip_runtime.h>
#include <hip/hip_fp16.h>

#define D       128
#define NROWS   100000
#define NTILES  (NROWS / 16)     // 6250 16-row tiles, exact
#define NBE     391              // E-blocks: 16 tiles (256 rows) each; 391*16 = 6256 >= 6250
#define NBN     (NROWS / 16)     // 6250 N-convert blocks
#define NPREP   (NBE + NBN)      // 6641; bid%17==0 -> E (exactly 391)

typedef __attribute__((ext_vector_type(8))) _Float16 f16x8;
typedef __attribute__((ext_vector_type(4))) float    f32x4;

union F16x8U { _Float16 h[8]; f16x8 v; };
union F32x4U { float f[4]; f32x4 v; };

typedef __attribute__((address_space(1))) const void gvoid;
typedef __attribute__((address_space(3))) void       lvoid;

// ---------------------------------------------------------------------------
// Kernel 0: metric -> fragment-ordered fp16 B-fragments (single term, 32 KB).
// Slot q = (kk*8+cf)*64+lane holds M[k0+j][col], col = cf*16+(lane&15),
// k0 = kk*32+(lane>>4)*8 — the verified 16x16x32 MFMA B-operand layout.
// ---------------------------------------------------------------------------
__global__ __launch_bounds__(256) void convert_M16(
    const float* __restrict__ M, _Float16* __restrict__ mh)
{
    const int q    = blockIdx.x * 256 + threadIdx.x;  // [0, 2048)
    const int kk   = q >> 9;
    const int cf   = (q >> 6) & 7;
    const int lane = q & 63;
    const int col  = cf * 16 + (lane & 15);
    const int k0   = kk * 32 + (lane >> 4) * 8;

    F16x8U h;
    #pragma unroll
    for (int j = 0; j < 8; ++j) h.h[j] = (_Float16)M[(k0 + j) * D + col];
    *(f16x8*)(mh + q * 8) = h.v;
}

// ---------------------------------------------------------------------------
// Kernel 1 (fused prep, 16:1 interleaved grid):
//   bid % 17 == 0 -> E-GEMM block: eid = bid/17, 16 tiles (256 rows)  [391]
//   else          -> N-convert block: nid = bid - bid/17 - 1, 16 rows [6250]
//
// E path: M (single-term fp16, 32 KB) staged once per block into LDS via
// global_load_lds + proven vmcnt(0)+__syncthreads drain. Then each wave
// free-runs 4 x 16-row tiles: 8 direct global->VGPR A-loads, cvt to fp16,
// 32 MFMAs with B read from LDS AT USE (conflict-free ds_read_b128 — the
// compiler cannot sink these into global reloads, fixing the recurring
// VGPR-sink failure), pi-ordered 16B stores. 32 KB LDS + launch_bounds
// (256,5) -> 5 blocks/CU = 20 waves/CU; co-resident N-waves keep HBM fed
// through E load shadows.
//
// N path: row = nid*16 + (tid>>4); 8 dword loads at stride 64B (coalesced
// per 16-lane group) -> one pi-ordered 16B store. pi(c) = (c&15)*8 + (c>>4).
// ---------------------------------------------------------------------------
__global__ __launch_bounds__(256, 5) void prep_fused(
    const float* __restrict__ E, const float* __restrict__ N,
    const _Float16* __restrict__ mh,
    _Float16* __restrict__ Ep, _Float16* __restrict__ Np)
{
    __shared__ _Float16 sm[2048 * 8];   // 32 KB, B-fragment slots

    const int tid = threadIdx.x;
    const int bid = (int)blockIdx.x;

    if (bid % 17 != 0) {
        // ---- N-convert ----
        const int nid = bid - bid / 17 - 1;             // 0..NBN-1
        const int l16 = tid & 15;
        const int row = nid * 16 + (tid >> 4);          // exact: NBN*16 = NROWS
        const float* src = N + (size_t)row * D + l16;
        F16x8U o;
        #pragma unroll
        for (int k = 0; k < 8; ++k) o.h[k] = (_Float16)src[16 * k];
        *(f16x8*)(Np + (size_t)row * D + l16 * 8) = o.v;
        return;
    }

    // ---- E-GEMM ----
    const int eid  = bid / 17;                          // 0..390
    const int lane = tid & 63;
    const int w    = tid >> 6;
    const int lrow = lane & 15;
    const int lk   = lane >> 4;

    // Stage M fragments (32 KB, linear; wave-uniform LDS base + lane*16).
    #pragma unroll
    for (int it = 0; it < 8; ++it) {
        const int slot = it * 256 + w * 64 + lane;
        __builtin_amdgcn_global_load_lds(
            (gvoid*)(mh + slot * 8), (lvoid*)(sm + (it * 256 + w * 64) * 8),
            16, 0, 0);
    }
    asm volatile("s_waitcnt vmcnt(0)" ::: "memory");
    __syncthreads();

    const f16x8* Bh = (const f16x8*)sm;   // [(kk*8+cf)*64 + lane]

    #pragma unroll 1
    for (int rt = 0; rt < 4; ++rt) {
        const int tb = eid * 16 + rt * 4 + w;           // wave's tile
        if (tb >= NTILES) break;
        const int row = tb * 16 + lrow;

        // A-loads: 8 x dwordx4 in flight (rows tb*16..+15, full line coverage).
        f32x4 ax[4], ay[4];
        #pragma unroll
        for (int kk = 0; kk < 4; ++kk) {
            const float* p = E + (size_t)row * D + kk * 32 + lk * 8;
            ax[kk] = *(const f32x4*)p;
            ay[kk] = *(const f32x4*)(p + 4);
        }

        f32x4 acc[8];
        #pragma unroll
        for (int cf = 0; cf < 8; ++cf) acc[cf] = (f32x4){0.f, 0.f, 0.f, 0.f};

        #pragma unroll
        for (int kk = 0; kk < 4; ++kk) {
            F16x8U a16;
            F32x4U x, y; x.v = ax[kk]; y.v = ay[kk];
            #pragma unroll
            for (int j = 0; j < 4; ++j) {
                a16.h[j]     = (_Float16)x.f[j];
                a16.h[j + 4] = (_Float16)y.f[j];
            }
            #pragma unroll
            for (int cf = 0; cf < 8; ++cf)
                acc[cf] = __builtin_amdgcn_mfma_f32_16x16x32_f16(
                    a16.v, Bh[(kk * 8 + cf) * 64 + lane], acc[cf], 0, 0, 0);
        }

        // Epilogue (R9-proven): C/D col = lane&15, row = lk*4+i. pi makes the
        // 8 cf-values contiguous: one f16x8 store; 16 lanes tile the 256B row.
        #pragma unroll
        for (int i = 0; i < 4; ++i) {
            const int ro = tb * 16 + lk * 4 + i;
            F16x8U o;
            #pragma unroll
            for (int cf = 0; cf < 8; ++cf) o.h[cf] = (_Float16)acc[cf][i];
            *(f16x8*)(Ep + (size_t)ro * D + lrow * 8) = o.v;
        }
    }
}

// ---------------------------------------------------------------------------
// Kernel 2: out[b] = sigmoid(2 * dot(Ep[xs[b]], Np[ys[b]]) - 1).
// Both tables fp16 in pi order (dot order-invariant). 16 lanes/output,
// 2 outputs per lane-group, one dwordx4 per table per output, fp32 accum.
// Proven fast (R7/R10).
// ---------------------------------------------------------------------------
__global__ __launch_bounds__(256) void gather_dot16(
    const int* __restrict__ xs, const int* __restrict__ ys,
    const _Float16* __restrict__ Ep, const _Float16* __restrict__ Np,
    float* __restrict__ out)
{
    const int tid = threadIdx.x;
    const int o0  = blockIdx.x * 32 + (tid >> 4) * 2;
    const int l   = tid & 15;

    const int x0 = xs[o0], x1 = xs[o0 + 1];
    const int y0 = ys[o0], y1 = ys[o0 + 1];

    const f16x8 a0 = *(const f16x8*)(Ep + (size_t)x0 * D + l * 8);
    const f16x8 b0 = *(const f16x8*)(Np + (size_t)y0 * D + l * 8);
    const f16x8 a1 = *(const f16x8*)(Ep + (size_t)x1 * D + l * 8);
    const f16x8 b1 = *(const f16x8*)(Np + (size_t)y1 * D + l * 8);

    float r0 = 0.f, r1 = 0.f;
    #pragma unroll
    for (int j = 0; j < 8; ++j) {
        r0 += (float)a0[j] * (float)b0[j];
        r1 += (float)a1[j] * (float)b1[j];
    }

    r0 += __shfl_xor(r0, 1); r1 += __shfl_xor(r1, 1);
    r0 += __shfl_xor(r0, 2); r1 += __shfl_xor(r1, 2);
    r0 += __shfl_xor(r0, 4); r1 += __shfl_xor(r1, 4);
    r0 += __shfl_xor(r0, 8); r1 += __shfl_xor(r1, 8);

    if (l == 0) {
        float2 v;
        v.x = 1.0f / (1.0f + __expf(1.0f - 2.0f * r0));
        v.y = 1.0f / (1.0f + __expf(1.0f - 2.0f * r1));
        *(float2*)(out + o0) = v;
    }
}

extern "C" void kernel_launch(void* const* d_in, const int* in_sizes, int n_in,
                              void* d_out, int out_size, void* d_ws, size_t ws_size,
                              hipStream_t stream) {
    const int*   xs     = (const int*)d_in[0];
    const int*   ys     = (const int*)d_in[1];
    const float* metric = (const float*)d_in[2];
    const float* EMBEDM = (const float*)d_in[3];
    const float* NEGEM  = (const float*)d_in[4];
    float*       out    = (float*)d_out;

    const int B = in_sizes[0];  // 262144

    // d_ws layout: Np16 25.6MB @0, Ep16 25.6MB @32MB, M-fragments 32KB @64MB.
    char* ws = (char*)d_ws;
    _Float16* Np = (_Float16*)ws;
    _Float16* Ep = (_Float16*)(ws + (32u << 20));
    _Float16* mh = (_Float16*)(ws + (64u << 20));

    convert_M16<<<8, 256, 0, stream>>>(metric, mh);

    prep_fused<<<NPREP, 256, 0, stream>>>(EMBEDM, NEGEM, mh, Ep, Np);

    gather_dot16<<<B / 32, 256, 0, stream>>>(xs, ys, Ep, Np, out);
}

// Round 14
// 56.222 us; speedup vs baseline: 1.3813x; 1.0017x over previous
//
#include <hip/hip_runtime.h>
#include <hip/hip_fp16.h>

#define D       128
#define NROWS   100000
#define NTILES  (NROWS / 16)     // 6250 16-row tiles, exact
#define NBE     391              // E-blocks: 16 tiles (256 rows) each; 391*16 = 6256 >= 6250
#define NBN     (NROWS / 16)     // 6250 N-convert blocks
#define NPREP   (NBE + NBN)      // 6641; bid%17==0 -> E (exactly 391)

typedef __attribute__((ext_vector_type(8))) _Float16 f16x8;
typedef __attribute__((ext_vector_type(4))) float    f32x4;

union F16x8U { _Float16 h[8]; f16x8 v; };
union F32x4U { float f[4]; f32x4 v; };

typedef __attribute__((address_space(1))) const void gvoid;
typedef __attribute__((address_space(3))) void       lvoid;

// ---------------------------------------------------------------------------
// Kernel 0: metric -> fragment-ordered fp16 B-fragments (single term, 32 KB).
// Slot q = (kk*8+cf)*64+lane holds M[k0+j][col], col = cf*16+(lane&15),
// k0 = kk*32+(lane>>4)*8 — the verified 16x16x32 MFMA B-operand layout.
// ---------------------------------------------------------------------------
__global__ __launch_bounds__(256) void convert_M16(
    const float* __restrict__ M, _Float16* __restrict__ mh)
{
    const int q    = blockIdx.x * 256 + threadIdx.x;  // [0, 2048)
    const int kk   = q >> 9;
    const int cf   = (q >> 6) & 7;
    const int lane = q & 63;
    const int col  = cf * 16 + (lane & 15);
    const int k0   = kk * 32 + (lane >> 4) * 8;

    F16x8U h;
    #pragma unroll
    for (int j = 0; j < 8; ++j) h.h[j] = (_Float16)M[(k0 + j) * D + col];
    *(f16x8*)(mh + q * 8) = h.v;
}

// ---------------------------------------------------------------------------
// Kernel 1 (fused prep, 16:1 interleaved grid):
//   bid % 17 == 0 -> E-GEMM block: eid = bid/17, 16 tiles (256 rows)  [391]
//   else          -> N-convert block: nid = bid - bid/17 - 1, 16 rows [6250]
//
// E path: M (single-term fp16, 32 KB) staged once per block into LDS via
// global_load_lds + proven vmcnt(0)+__syncthreads drain. Then each wave
// free-runs 4 x 16-row tiles: 8 direct global->VGPR A-loads, cvt to fp16,
// 32 MFMAs with B read from LDS AT USE (conflict-free ds_read_b128 — the
// compiler cannot sink these into global reloads, fixing the recurring
// VGPR-sink failure), pi-ordered 16B stores. 32 KB LDS + launch_bounds
// (256,5) -> 5 blocks/CU = 20 waves/CU; co-resident N-waves keep HBM fed
// through E load shadows.
//
// N path: row = nid*16 + (tid>>4); 8 dword loads at stride 64B (coalesced
// per 16-lane group) -> one pi-ordered 16B store. pi(c) = (c&15)*8 + (c>>4).
// ---------------------------------------------------------------------------
__global__ __launch_bounds__(256, 5) void prep_fused(
    const float* __restrict__ E, const float* __restrict__ N,
    const _Float16* __restrict__ mh,
    _Float16* __restrict__ Ep, _Float16* __restrict__ Np)
{
    __shared__ _Float16 sm[2048 * 8];   // 32 KB, B-fragment slots

    const int tid = threadIdx.x;
    const int bid = (int)blockIdx.x;

    if (bid % 17 != 0) {
        // ---- N-convert ----
        const int nid = bid - bid / 17 - 1;             // 0..NBN-1
        const int l16 = tid & 15;
        const int row = nid * 16 + (tid >> 4);          // exact: NBN*16 = NROWS
        const float* src = N + (size_t)row * D + l16;
        F16x8U o;
        #pragma unroll
        for (int k = 0; k < 8; ++k) o.h[k] = (_Float16)src[16 * k];
        *(f16x8*)(Np + (size_t)row * D + l16 * 8) = o.v;
        return;
    }

    // ---- E-GEMM ----
    const int eid  = bid / 17;                          // 0..390
    const int lane = tid & 63;
    const int w    = tid >> 6;
    const int lrow = lane & 15;
    const int lk   = lane >> 4;

    // Stage M fragments (32 KB, linear; wave-uniform LDS base + lane*16).
    #pragma unroll
    for (int it = 0; it < 8; ++it) {
        const int slot = it * 256 + w * 64 + lane;
        __builtin_amdgcn_global_load_lds(
            (gvoid*)(mh + slot * 8), (lvoid*)(sm + (it * 256 + w * 64) * 8),
            16, 0, 0);
    }
    asm volatile("s_waitcnt vmcnt(0)" ::: "memory");
    __syncthreads();

    const f16x8* Bh = (const f16x8*)sm;   // [(kk*8+cf)*64 + lane]

    #pragma unroll 1
    for (int rt = 0; rt < 4; ++rt) {
        const int tb = eid * 16 + rt * 4 + w;           // wave's tile
        if (tb >= NTILES) break;
        const int row = tb * 16 + lrow;

        // A-loads: 8 x dwordx4 in flight (rows tb*16..+15, full line coverage).
        f32x4 ax[4], ay[4];
        #pragma unroll
        for (int kk = 0; kk < 4; ++kk) {
            const float* p = E + (size_t)row * D + kk * 32 + lk * 8;
            ax[kk] = *(const f32x4*)p;
            ay[kk] = *(const f32x4*)(p + 4);
        }

        f32x4 acc[8];
        #pragma unroll
        for (int cf = 0; cf < 8; ++cf) acc[cf] = (f32x4){0.f, 0.f, 0.f, 0.f};

        #pragma unroll
        for (int kk = 0; kk < 4; ++kk) {
            F16x8U a16;
            F32x4U x, y; x.v = ax[kk]; y.v = ay[kk];
            #pragma unroll
            for (int j = 0; j < 4; ++j) {
                a16.h[j]     = (_Float16)x.f[j];
                a16.h[j + 4] = (_Float16)y.f[j];
            }
            #pragma unroll
            for (int cf = 0; cf < 8; ++cf)
                acc[cf] = __builtin_amdgcn_mfma_f32_16x16x32_f16(
                    a16.v, Bh[(kk * 8 + cf) * 64 + lane], acc[cf], 0, 0, 0);
        }

        // Epilogue (R9-proven): C/D col = lane&15, row = lk*4+i. pi makes the
        // 8 cf-values contiguous: one f16x8 store; 16 lanes tile the 256B row.
        #pragma unroll
        for (int i = 0; i < 4; ++i) {
            const int ro = tb * 16 + lk * 4 + i;
            F16x8U o;
            #pragma unroll
            for (int cf = 0; cf < 8; ++cf) o.h[cf] = (_Float16)acc[cf][i];
            *(f16x8*)(Ep + (size_t)ro * D + lrow * 8) = o.v;
        }
    }
}

// ---------------------------------------------------------------------------
// Kernel 2: out[b] = sigmoid(2 * dot(Ep[xs[b]], Np[ys[b]]) - 1).
// Both tables fp16 in pi order (dot order-invariant). 16 lanes/output,
// 2 outputs per lane-group, one dwordx4 per table per output, fp32 accum.
// Proven fast (R7/R10).
// ---------------------------------------------------------------------------
__global__ __launch_bounds__(256) void gather_dot16(
    const int* __restrict__ xs, const int* __restrict__ ys,
    const _Float16* __restrict__ Ep, const _Float16* __restrict__ Np,
    float* __restrict__ out)
{
    const int tid = threadIdx.x;
    const int o0  = blockIdx.x * 32 + (tid >> 4) * 2;
    const int l   = tid & 15;

    const int x0 = xs[o0], x1 = xs[o0 + 1];
    const int y0 = ys[o0], y1 = ys[o0 + 1];

    const f16x8 a0 = *(const f16x8*)(Ep + (size_t)x0 * D + l * 8);
    const f16x8 b0 = *(const f16x8*)(Np + (size_t)y0 * D + l * 8);
    const f16x8 a1 = *(const f16x8*)(Ep + (size_t)x1 * D + l * 8);
    const f16x8 b1 = *(const f16x8*)(Np + (size_t)y1 * D + l * 8);

    float r0 = 0.f, r1 = 0.f;
    #pragma unroll
    for (int j = 0; j < 8; ++j) {
        r0 += (float)a0[j] * (float)b0[j];
        r1 += (float)a1[j] * (float)b1[j];
    }

    r0 += __shfl_xor(r0, 1); r1 += __shfl_xor(r1, 1);
    r0 += __shfl_xor(r0, 2); r1 += __shfl_xor(r1, 2);
    r0 += __shfl_xor(r0, 4); r1 += __shfl_xor(r1, 4);
    r0 += __shfl_xor(r0, 8); r1 += __shfl_xor(r1, 8);

    if (l == 0) {
        float2 v;
        v.x = 1.0f / (1.0f + __expf(1.0f - 2.0f * r0));
        v.y = 1.0f / (1.0f + __expf(1.0f - 2.0f * r1));
        *(float2*)(out + o0) = v;
    }
}

extern "C" void kernel_launch(void* const* d_in, const int* in_sizes, int n_in,
                              void* d_out, int out_size, void* d_ws, size_t ws_size,
                              hipStream_t stream) {
    const int*   xs     = (const int*)d_in[0];
    const int*   ys     = (const int*)d_in[1];
    const float* metric = (const float*)d_in[2];
    const float* EMBEDM = (const float*)d_in[3];
    const float* NEGEM  = (const float*)d_in[4];
    float*       out    = (float*)d_out;

    const int B = in_sizes[0];  // 262144

    // d_ws layout: Np16 25.6MB @0, Ep16 25.6MB @32MB, M-fragments 32KB @64MB.
    char* ws = (char*)d_ws;
    _Float16* Np = (_Float16*)ws;
    _Float16* Ep = (_Float16*)(ws + (32u << 20));
    _Float16* mh = (_Float16*)(ws + (64u << 20));

    convert_M16<<<8, 256, 0, stream>>>(metric, mh);

    prep_fused<<<NPREP, 256, 0, stream>>>(EMBEDM, NEGEM, mh, Ep, Np);

    gather_dot16<<<B / 32, 256, 0, stream>>>(xs, ys, Ep, Np, out);
}

// Round 15
// 53.070 us; speedup vs baseline: 1.4633x; 1.0594x over previous
//
#include <hip/hip_runtime.h>
#include <hip/hip_fp16.h>

#define D        128
#define NROWS    100000
#define NET      (NROWS / 16)          // 6250 E-tiles (16 rows each)
#define NNT      (NROWS / 4)           // 25000 N-units (4 rows each)
#define NUNITS   (NET + NNT)           // 31250 wave-units
#define GRID_P   1280                  // 5 blocks/CU exactly (32KB LDS each)
#define NWAVES   (GRID_P * 4)          // 5120 grid-striding waves

typedef __attribute__((ext_vector_type(8))) _Float16 f16x8;
typedef __attribute__((ext_vector_type(4))) float    f32x4;

union F16x8U { _Float16 h[8]; f16x8 v; };
union F32x4U { float f[4]; f32x4 v; };

typedef __attribute__((address_space(1))) const void gvoid;
typedef __attribute__((address_space(3))) void       lvoid;

// ---------------------------------------------------------------------------
// Kernel 0: metric -> fragment-ordered fp16 B-fragments (single term, 32 KB).
// Slot q = (kk*8+cf)*64+lane holds M[k0+j][col], col = cf*16+(lane&15),
// k0 = kk*32+(lane>>4)*8 — the verified 16x16x32 MFMA B-operand layout.
// ---------------------------------------------------------------------------
__global__ __launch_bounds__(256) void convert_M16(
    const float* __restrict__ M, _Float16* __restrict__ mh)
{
    const int q    = blockIdx.x * 256 + threadIdx.x;  // [0, 2048)
    const int kk   = q >> 9;
    const int cf   = (q >> 6) & 7;
    const int lane = q & 63;
    const int col  = cf * 16 + (lane & 15);
    const int k0   = kk * 32 + (lane >> 4) * 8;

    F16x8U h;
    #pragma unroll
    for (int j = 0; j < 8; ++j) h.h[j] = (_Float16)M[(k0 + j) * D + col];
    *(f16x8*)(mh + q * 8) = h.v;
}

// ---------------------------------------------------------------------------
// Kernel 1: persistent balanced prep. 1280 blocks x 4 waves; M (32 KB fp16
// fragments) staged once per block (global_load_lds + proven vmcnt(0)+
// __syncthreads drain), then each WAVE free-runs a grid-stride loop over
// 31250 uniform units with NO further barriers:
//   u < NET      : E-tile u (16 rows): 8 dwordx4 A-loads, cvt fp16, 32 MFMA
//                  (B from LDS at use — un-sinkable), 4 pi-ordered f16x8
//                  stores of Ep.   pi(c) = (c&15)*8 + (c>>4).
//   u >= NET     : N-unit (4 rows): lane (row=lane>>4, l16=lane&15) reads 8
//                  dwords at stride 64B -> one pi-ordered f16x8 store of Np.
// Uniform block duration -> no tail; 20 streaming waves/CU for full MLP.
// ---------------------------------------------------------------------------
__global__ __launch_bounds__(256, 5) void prep_all(
    const float* __restrict__ E, const float* __restrict__ N,
    const _Float16* __restrict__ mh,
    _Float16* __restrict__ Ep, _Float16* __restrict__ Np)
{
    __shared__ _Float16 sm[2048 * 8];   // 32 KB, B-fragment slots

    const int tid  = threadIdx.x;
    const int lane = tid & 63;
    const int w    = tid >> 6;
    const int lrow = lane & 15;
    const int lk   = lane >> 4;

    // Stage M fragments (32 KB, linear; wave-uniform LDS base + lane*16).
    #pragma unroll
    for (int it = 0; it < 8; ++it) {
        const int slot = it * 256 + w * 64 + lane;
        __builtin_amdgcn_global_load_lds(
            (gvoid*)(mh + slot * 8), (lvoid*)(sm + (it * 256 + w * 64) * 8),
            16, 0, 0);
    }
    asm volatile("s_waitcnt vmcnt(0)" ::: "memory");
    __syncthreads();

    const f16x8* Bh = (const f16x8*)sm;   // [(kk*8+cf)*64 + lane]

    const int gwave = (int)blockIdx.x * 4 + w;   // 0..5119

    #pragma unroll 1
    for (int u = gwave; u < NUNITS; u += NWAVES) {
        if (u < NET) {
            // ---- E-tile: rows u*16 .. u*16+15 ----
            const int row = u * 16 + lrow;

            f32x4 ax[4], ay[4];
            #pragma unroll
            for (int kk = 0; kk < 4; ++kk) {
                const float* p = E + (size_t)row * D + kk * 32 + lk * 8;
                ax[kk] = *(const f32x4*)p;
                ay[kk] = *(const f32x4*)(p + 4);
            }

            f32x4 acc[8];
            #pragma unroll
            for (int cf = 0; cf < 8; ++cf) acc[cf] = (f32x4){0.f, 0.f, 0.f, 0.f};

            #pragma unroll
            for (int kk = 0; kk < 4; ++kk) {
                F16x8U a16;
                F32x4U x, y; x.v = ax[kk]; y.v = ay[kk];
                #pragma unroll
                for (int j = 0; j < 4; ++j) {
                    a16.h[j]     = (_Float16)x.f[j];
                    a16.h[j + 4] = (_Float16)y.f[j];
                }
                #pragma unroll
                for (int cf = 0; cf < 8; ++cf)
                    acc[cf] = __builtin_amdgcn_mfma_f32_16x16x32_f16(
                        a16.v, Bh[(kk * 8 + cf) * 64 + lane], acc[cf], 0, 0, 0);
            }

            // Epilogue: C/D col = lane&15, row = lk*4+i (m89-verified); pi
            // makes the 8 cf-values contiguous -> one f16x8 store per i.
            #pragma unroll
            for (int i = 0; i < 4; ++i) {
                const int ro = u * 16 + lk * 4 + i;
                F16x8U o;
                #pragma unroll
                for (int cf = 0; cf < 8; ++cf) o.h[cf] = (_Float16)acc[cf][i];
                *(f16x8*)(Ep + (size_t)ro * D + lrow * 8) = o.v;
            }
        } else {
            // ---- N-unit: rows (u-NET)*4 .. +3 ----
            const int row = (u - NET) * 4 + lk;
            const float* src = N + (size_t)row * D + lrow;
            F16x8U o;
            #pragma unroll
            for (int k = 0; k < 8; ++k) o.h[k] = (_Float16)src[16 * k];
            *(f16x8*)(Np + (size_t)row * D + lrow * 8) = o.v;
        }
    }
}

// ---------------------------------------------------------------------------
// Kernel 2: out[b] = sigmoid(2 * dot(Ep[xs[b]], Np[ys[b]]) - 1).
// Both tables fp16 in pi order (dot order-invariant). 16 lanes/output,
// 2 outputs per lane-group, one dwordx4 per table per output, fp32 accum.
// Proven fast (R7/R14, ~13 us).
// ---------------------------------------------------------------------------
__global__ __launch_bounds__(256) void gather_dot16(
    const int* __restrict__ xs, const int* __restrict__ ys,
    const _Float16* __restrict__ Ep, const _Float16* __restrict__ Np,
    float* __restrict__ out)
{
    const int tid = threadIdx.x;
    const int o0  = blockIdx.x * 32 + (tid >> 4) * 2;
    const int l   = tid & 15;

    const int x0 = xs[o0], x1 = xs[o0 + 1];
    const int y0 = ys[o0], y1 = ys[o0 + 1];

    const f16x8 a0 = *(const f16x8*)(Ep + (size_t)x0 * D + l * 8);
    const f16x8 b0 = *(const f16x8*)(Np + (size_t)y0 * D + l * 8);
    const f16x8 a1 = *(const f16x8*)(Ep + (size_t)x1 * D + l * 8);
    const f16x8 b1 = *(const f16x8*)(Np + (size_t)y1 * D + l * 8);

    float r0 = 0.f, r1 = 0.f;
    #pragma unroll
    for (int j = 0; j < 8; ++j) {
        r0 += (float)a0[j] * (float)b0[j];
        r1 += (float)a1[j] * (float)b1[j];
    }

    r0 += __shfl_xor(r0, 1); r1 += __shfl_xor(r1, 1);
    r0 += __shfl_xor(r0, 2); r1 += __shfl_xor(r1, 2);
    r0 += __shfl_xor(r0, 4); r1 += __shfl_xor(r1, 4);
    r0 += __shfl_xor(r0, 8); r1 += __shfl_xor(r1, 8);

    if (l == 0) {
        float2 v;
        v.x = 1.0f / (1.0f + __expf(1.0f - 2.0f * r0));
        v.y = 1.0f / (1.0f + __expf(1.0f - 2.0f * r1));
        *(float2*)(out + o0) = v;
    }
}

extern "C" void kernel_launch(void* const* d_in, const int* in_sizes, int n_in,
                              void* d_out, int out_size, void* d_ws, size_t ws_size,
                              hipStream_t stream) {
    const int*   xs     = (const int*)d_in[0];
    const int*   ys     = (const int*)d_in[1];
    const float* metric = (const float*)d_in[2];
    const float* EMBEDM = (const float*)d_in[3];
    const float* NEGEM  = (const float*)d_in[4];
    float*       out    = (float*)d_out;

    const int B = in_sizes[0];  // 262144

    // d_ws layout: Np16 25.6MB @0, Ep16 25.6MB @32MB, M-fragments 32KB @64MB.
    char* ws = (char*)d_ws;
    _Float16* Np = (_Float16*)ws;
    _Float16* Ep = (_Float16*)(ws + (32u << 20));
    _Float16* mh = (_Float16*)(ws + (64u << 20));

    convert_M16<<<8, 256, 0, stream>>>(metric, mh);

    prep_all<<<GRID_P, 256, 0, stream>>>(EMBEDM, NEGEM, mh, Ep, Np);

    gather_dot16<<<B / 32, 256, 0, stream>>>(xs, ys, Ep, Np, out);
}

// Round 16
// 52.087 us; speedup vs baseline: 1.4910x; 1.0189x over previous
//
#include <hip/hip_runtime.h>
#include <hip/hip_fp16.h>

#define D        128
#define NROWS    100000
#define NET      (NROWS / 16)      // 6250 E-tiles (16 rows each), exact
#define NUNITS   (2 * NET)         // 12500 units: even -> E-tile, odd -> N-unit
#define GRID_P   768               // 3 blocks/CU (48 KB LDS each)
#define NWAVES   (GRID_P * 4)      // 3072 grid-striding waves

typedef __attribute__((ext_vector_type(8))) _Float16 f16x8;
typedef __attribute__((ext_vector_type(4))) _Float16 f16x4;
typedef __attribute__((ext_vector_type(4))) float    f32x4;

union F16x8U { _Float16 h[8]; f16x8 v; };
union F16x4U { _Float16 h[4]; f16x4 v; };
union F32x4U { float f[4]; f32x4 v; };

typedef __attribute__((address_space(1))) const void gvoid;
typedef __attribute__((address_space(3))) void       lvoid;

// ---------------------------------------------------------------------------
// Kernel 0: metric -> fragment-ordered fp16 B-fragments (single term, 32 KB).
// Slot q = (kk*8+cf)*64+lane holds M[k0+j][col], col = cf*16+(lane&15),
// k0 = kk*32+(lane>>4)*8 — the verified 16x16x32 MFMA B-operand layout.
// ---------------------------------------------------------------------------
__global__ __launch_bounds__(256) void convert_M16(
    const float* __restrict__ M, _Float16* __restrict__ mh)
{
    const int q    = blockIdx.x * 256 + threadIdx.x;  // [0, 2048)
    const int kk   = q >> 9;
    const int cf   = (q >> 6) & 7;
    const int lane = q & 63;
    const int col  = cf * 16 + (lane & 15);
    const int k0   = kk * 32 + (lane >> 4) * 8;

    F16x8U h;
    #pragma unroll
    for (int j = 0; j < 8; ++j) h.h[j] = (_Float16)M[(k0 + j) * D + col];
    *(f16x8*)(mh + q * 8) = h.v;
}

// ---------------------------------------------------------------------------
// Kernel 1: persistent prep; ALL global reads wave-contiguous (lane i reads
// base + i*16B; 1KB/instruction), data repacked through a WAVE-PRIVATE 4KB
// LDS scratch (own-wave lgkmcnt only — no barriers in the hot loop).
//
// E-tile (16 rows = 8KB fp32): 8 contiguous dwordx4 loads -> cvt fp16 ->
//   ds_write_b64 at [row][slot^row] (XOR swizzle) -> per kk: conflict-free
//   ds_read_b128 A-frag [lrow][(kk*4+lk)^lrow] (= cols kk*32+lk*8..+7) ->
//   32 MFMAs (B from the block-shared 32KB M-fragment LDS) -> pi-ordered
//   f16x8 epilogue stores (R15-proven).  pi(c) = (c&15)*8 + (c>>4).
//
// N-unit (16 rows): 8 contiguous dwordx4 loads -> cvt -> pi-scatter
//   ds_write_b16 [row][pi(c)] -> linear ds_read_b128 -> contiguous 1KB
//   global stores.
//
// Units alternate E/N by parity so both streams mix on every CU.
// LDS: 32KB (M) + 4 waves x 4KB (scratch) = 48KB -> 3 blocks/CU, 12 waves.
// ---------------------------------------------------------------------------
__global__ __launch_bounds__(256, 3) void prep_all2(
    const float* __restrict__ E, const float* __restrict__ N,
    const _Float16* __restrict__ mh,
    _Float16* __restrict__ Ep, _Float16* __restrict__ Np)
{
    __shared__ _Float16 smM[2048 * 8];   // 32 KB M B-fragment slots
    __shared__ _Float16 scr[4][2048];    // 4 KB per wave

    const int tid  = threadIdx.x;
    const int lane = tid & 63;
    const int w    = tid >> 6;
    const int lrow = lane & 15;
    const int lk   = lane >> 4;

    // Stage M fragments once per block (proven drain).
    #pragma unroll
    for (int it = 0; it < 8; ++it) {
        const int slot = it * 256 + w * 64 + lane;
        __builtin_amdgcn_global_load_lds(
            (gvoid*)(mh + slot * 8), (lvoid*)(smM + (it * 256 + w * 64) * 8),
            16, 0, 0);
    }
    asm volatile("s_waitcnt vmcnt(0)" ::: "memory");
    __syncthreads();

    const f16x8* Bh = (const f16x8*)smM;   // [(kk*8+cf)*64 + lane]
    _Float16*    S  = scr[w];

    const int gw = (int)blockIdx.x * 4 + w;   // 0..3071

    #pragma unroll 1
    for (int u = gw; u < NUNITS; u += NWAVES) {
        const int t16 = u >> 1;               // tile/unit row-block 0..6249

        if ((u & 1) == 0) {
            // ---------------- E-tile ----------------
            // Contiguous loads + cvt + swizzled scratch writes.
            #pragma unroll
            for (int i = 0; i < 8; ++i) {
                const int f   = i * 256 + lane * 4;   // flat float idx in tile
                const int row = f >> 7;
                const int col = f & 127;
                F32x4U v; v.v = *(const f32x4*)(E + (size_t)t16 * 2048 + f);
                F16x4U h4;
                h4.h[0] = (_Float16)v.f[0]; h4.h[1] = (_Float16)v.f[1];
                h4.h[2] = (_Float16)v.f[2]; h4.h[3] = (_Float16)v.f[3];
                const int tsl = (col >> 3) ^ row;     // XOR swizzle, bijective
                *(f16x4*)(S + row * 128 + tsl * 8 + (col & 7)) = h4.v;
            }
            asm volatile("s_waitcnt lgkmcnt(0)" ::: "memory");
            __builtin_amdgcn_sched_barrier(0);

            f32x4 acc[8];
            #pragma unroll
            for (int cf = 0; cf < 8; ++cf) acc[cf] = (f32x4){0.f, 0.f, 0.f, 0.f};

            #pragma unroll
            for (int kk = 0; kk < 4; ++kk) {
                // A-frag: row lrow, slot (kk*4+lk)^lrow -> cols kk*32+lk*8..+7
                const f16x8 a16 =
                    *(const f16x8*)(S + lrow * 128 + ((kk * 4 + lk) ^ lrow) * 8);
                #pragma unroll
                for (int cf = 0; cf < 8; ++cf)
                    acc[cf] = __builtin_amdgcn_mfma_f32_16x16x32_f16(
                        a16, Bh[(kk * 8 + cf) * 64 + lane], acc[cf], 0, 0, 0);
            }

            // Epilogue (proven): C/D col = lrow, row = lk*4+i; pi -> one
            // f16x8 store per i.
            #pragma unroll
            for (int i = 0; i < 4; ++i) {
                const int ro = t16 * 16 + lk * 4 + i;
                F16x8U o;
                #pragma unroll
                for (int cf = 0; cf < 8; ++cf) o.h[cf] = (_Float16)acc[cf][i];
                *(f16x8*)(Ep + (size_t)ro * D + lrow * 8) = o.v;
            }
        } else {
            // ---------------- N-unit ----------------
            // Contiguous loads + cvt + pi-scatter scratch writes.
            #pragma unroll
            for (int i = 0; i < 8; ++i) {
                const int f   = i * 256 + lane * 4;
                const int row = f >> 7;
                const int col = f & 127;
                F32x4U v; v.v = *(const f32x4*)(N + (size_t)t16 * 2048 + f);
                const int lo = col & 15;      // multiple of 4
                const int hi = col >> 4;
                _Float16* base = S + row * 128 + hi;
                base[(lo    ) * 8] = (_Float16)v.f[0];
                base[(lo + 1) * 8] = (_Float16)v.f[1];
                base[(lo + 2) * 8] = (_Float16)v.f[2];
                base[(lo + 3) * 8] = (_Float16)v.f[3];
            }
            asm volatile("s_waitcnt lgkmcnt(0)" ::: "memory");
            __builtin_amdgcn_sched_barrier(0);

            // Linear read-back + contiguous 1KB stores.
            #pragma unroll
            for (int i = 0; i < 4; ++i) {
                const f16x8 t = *(const f16x8*)(S + i * 512 + lane * 8);
                *(f16x8*)(Np + (size_t)t16 * 2048 + i * 512 + lane * 8) = t;
            }
        }

        // Scratch reuse across iterations is safe: DS ops of a wave execute
        // in order, and all reads above are lgkm-drained before the next
        // unit's writes issue.
    }
}

// ---------------------------------------------------------------------------
// Kernel 2: out[b] = sigmoid(2 * dot(Ep[xs[b]], Np[ys[b]]) - 1).
// Both tables fp16 in pi order (dot order-invariant). 16 lanes/output,
// 2 outputs per lane-group, one dwordx4 per table per output, fp32 accum.
// Proven ~13 us.
// ---------------------------------------------------------------------------
__global__ __launch_bounds__(256) void gather_dot16(
    const int* __restrict__ xs, const int* __restrict__ ys,
    const _Float16* __restrict__ Ep, const _Float16* __restrict__ Np,
    float* __restrict__ out)
{
    const int tid = threadIdx.x;
    const int o0  = blockIdx.x * 32 + (tid >> 4) * 2;
    const int l   = tid & 15;

    const int x0 = xs[o0], x1 = xs[o0 + 1];
    const int y0 = ys[o0], y1 = ys[o0 + 1];

    const f16x8 a0 = *(const f16x8*)(Ep + (size_t)x0 * D + l * 8);
    const f16x8 b0 = *(const f16x8*)(Np + (size_t)y0 * D + l * 8);
    const f16x8 a1 = *(const f16x8*)(Ep + (size_t)x1 * D + l * 8);
    const f16x8 b1 = *(const f16x8*)(Np + (size_t)y1 * D + l * 8);

    float r0 = 0.f, r1 = 0.f;
    #pragma unroll
    for (int j = 0; j < 8; ++j) {
        r0 += (float)a0[j] * (float)b0[j];
        r1 += (float)a1[j] * (float)b1[j];
    }

    r0 += __shfl_xor(r0, 1); r1 += __shfl_xor(r1, 1);
    r0 += __shfl_xor(r0, 2); r1 += __shfl_xor(r1, 2);
    r0 += __shfl_xor(r0, 4); r1 += __shfl_xor(r1, 4);
    r0 += __shfl_xor(r0, 8); r1 += __shfl_xor(r1, 8);

    if (l == 0) {
        float2 v;
        v.x = 1.0f / (1.0f + __expf(1.0f - 2.0f * r0));
        v.y = 1.0f / (1.0f + __expf(1.0f - 2.0f * r1));
        *(float2*)(out + o0) = v;
    }
}

extern "C" void kernel_launch(void* const* d_in, const int* in_sizes, int n_in,
                              void* d_out, int out_size, void* d_ws, size_t ws_size,
                              hipStream_t stream) {
    const int*   xs     = (const int*)d_in[0];
    const int*   ys     = (const int*)d_in[1];
    const float* metric = (const float*)d_in[2];
    const float* EMBEDM = (const float*)d_in[3];
    const float* NEGEM  = (const float*)d_in[4];
    float*       out    = (float*)d_out;

    const int B = in_sizes[0];  // 262144

    // d_ws layout: Np16 25.6MB @0, Ep16 25.6MB @32MB, M-fragments 32KB @64MB.
    char* ws = (char*)d_ws;
    _Float16* Np = (_Float16*)ws;
    _Float16* Ep = (_Float16*)(ws + (32u << 20));
    _Float16* mh = (_Float16*)(ws + (64u << 20));

    convert_M16<<<8, 256, 0, stream>>>(metric, mh);

    prep_all2<<<GRID_P, 256, 0, stream>>>(EMBEDM, NEGEM, mh, Ep, Np);

    gather_dot16<<<B / 32, 256, 0, stream>>>(xs, ys, Ep, Np, out);
}